// Round 1
// 3087.025 us; speedup vs baseline: 1.0585x; 1.0585x over previous
//
#include <hip/hip_runtime.h>
#include <hip/hip_bf16.h>
#include <math.h>

// EncoderRNN on MI355X. Inputs fp32, output fp32.
// R12: (1) k_embed fused 3-product split GEMM (one K-sweep, convert once,
//      3x less fetch, ~2.3x less cvt VALU); (2) R partials 10 -> 5 via paired
//      GEMM chains in k_step (halves R traffic, frees 10.5 MB so the full-v
//      path fits at ~97 MB); (3) slots scale 64/32/16/8 to workspace so the
//      chunked fallback still uses the full machine.
//   k_uw: u/w/cbd (fp64). k_wsplit: W1 -> bf16 hi+lo, W2 -> hi.
//   k_embed: v=relu(video@Wemb^T+bemb) -> bf16 hi/lo, acc = Ah*Bh+Al*Bh+Ah*Bl
//   k_zx: zx[t*128+b] = v.u + cbd (fp64)
//   scan k=0..64:
//     k_step (160 blocks, unit = (pair p, ct)): pair chains 2 GEMMs, K=1024 ea
//       pair0: vh@w1ih_h + vl@w1ih_h        -> P0
//       pair1: vh@w1ih_l + h1r1h@w1hh_h     -> P1   (k==0: first GEMM only)
//       pair2: h1r1l@w1hh_h + h1r1h@w1hh_l  -> P2   (skip k==0)
//       pair3: h1r2h@w2ih_h + h1r2l@w2ih_h  -> P3
//       pair4: h2h@w2hh_h + h2l@w2hh_h      -> P4
//     k_elem (128 blocks): lstm1 gates = P0+P1(+P2 if k>0)+b1; lstm2 = P3+P4

typedef __attribute__((ext_vector_type(8))) short short8;
typedef __attribute__((ext_vector_type(4))) short short4v;
typedef __attribute__((ext_vector_type(4))) float f32x4;
typedef __hip_bfloat16 bf16;

__device__ __forceinline__ float sigm(float x) { return 1.0f / (1.0f + expf(-x)); }
__device__ __forceinline__ short bfbits(float x) {
  bf16 h = __float2bfloat16(x);
  return __builtin_bit_cast(short, h);
}
// fp32 x8 -> bf16 hi + residual lo in one pass (shared loads/conversions)
__device__ __forceinline__ void cvt8hl(const float* __restrict__ p,
                                       short8& hi, short8& lo)
{
  f32x4 a = *(const f32x4*)p;
  f32x4 b = *(const f32x4*)(p + 4);
#pragma unroll
  for (int j = 0; j < 8; ++j) {
    float x = (j < 4) ? a[j] : b[j - 4];
    bf16 h = __float2bfloat16(x);
    hi[j] = __builtin_bit_cast(short, h);
    lo[j] = bfbits(x - __bfloat162float(h));
  }
}

// ---------------------------------------------------------------------------
// 128x128 GEMM tile: C += A(128xK)*B(128xK)^T, bf16 sources, fp32 acc.
// Double-buffered XOR-swizzled LDS; 16x16x32 MFMA; 2x2 waves of 64x64.
// ---------------------------------------------------------------------------
__device__ __forceinline__ void gemm_bf16(
    const bf16* __restrict__ A, int lda,
    const bf16* __restrict__ B, int ldb,
    int nChunks, short* ls, f32x4 acc[4][4])
{
  const int tid  = threadIdx.x;
  const int lane = tid & 63;
  const int wave = tid >> 6;
  const int wr = (wave & 1) * 64;
  const int wc = (wave >> 1) * 64;
  const int m  = lane & 15;
  const int kg = lane >> 4;

  int srow[4], sseg[4], ssw[4];
#pragma unroll
  for (int i = 0; i < 4; ++i) {
    int linear = i * 256 + tid;
    srow[i] = linear >> 3;
    sseg[i] = linear & 7;
    ssw[i]  = (sseg[i] ^ (srow[i] & 7)) * 8;
  }

  short8 areg[4], breg[4];
#pragma unroll
  for (int i = 0; i < 4; ++i) {
    areg[i] = *(const short8*)(A + (size_t)srow[i] * lda + sseg[i] * 8);
    breg[i] = *(const short8*)(B + (size_t)srow[i] * ldb + sseg[i] * 8);
  }
#pragma unroll
  for (int i = 0; i < 4; ++i) {
    *(short8*)(ls + srow[i] * 64 + ssw[i])        = areg[i];
    *(short8*)(ls + 8192 + srow[i] * 64 + ssw[i]) = breg[i];
  }
  __syncthreads();

  for (int c = 0; c < nChunks; ++c) {
    if (c + 1 < nChunks) {
#pragma unroll
      for (int i = 0; i < 4; ++i) {
        areg[i] = *(const short8*)(A + (size_t)srow[i] * lda + (c + 1) * 64 + sseg[i] * 8);
        breg[i] = *(const short8*)(B + (size_t)srow[i] * ldb + (c + 1) * 64 + sseg[i] * 8);
      }
    }
    const short* la = ls + (c & 1) * 16384;
    const short* lb = la + 8192;
#pragma unroll
    for (int ks = 0; ks < 2; ++ks) {
      short8 af[4], bfr[4];
#pragma unroll
      for (int f = 0; f < 4; ++f) {
        int ar = wr + f * 16 + m;
        af[f]  = *(const short8*)(la + ar * 64 + (((ks * 4 + kg) ^ (ar & 7)) * 8));
        int br = wc + f * 16 + m;
        bfr[f] = *(const short8*)(lb + br * 64 + (((ks * 4 + kg) ^ (br & 7)) * 8));
      }
#pragma unroll
      for (int fr = 0; fr < 4; ++fr)
#pragma unroll
        for (int fc = 0; fc < 4; ++fc)
          acc[fr][fc] = __builtin_amdgcn_mfma_f32_16x16x32_bf16(af[fr], bfr[fc], acc[fr][fc], 0, 0, 0);
    }
    if (c + 1 < nChunks) {
      short* lw = ls + ((c + 1) & 1) * 16384;
#pragma unroll
      for (int i = 0; i < 4; ++i) {
        *(short8*)(lw + srow[i] * 64 + ssw[i])        = areg[i];
        *(short8*)(lw + 8192 + srow[i] * 64 + ssw[i]) = breg[i];
      }
    }
    __syncthreads();
  }
}

// C/D frag layout (m89/m91-verified): col = lane&15, row = (lane>>4)*4 + reg.
template <typename F>
__device__ __forceinline__ void epilogue(const f32x4 acc[4][4], F&& body)
{
  const int tid = threadIdx.x, lane = tid & 63, wave = tid >> 6;
  const int m = lane & 15, kg = lane >> 4;
  const int wr = (wave & 1) * 64, wc = (wave >> 1) * 64;
#pragma unroll
  for (int fr = 0; fr < 4; ++fr)
#pragma unroll
    for (int fc = 0; fc < 4; ++fc)
#pragma unroll
      for (int r = 0; r < 4; ++r)
        body(wr + fr * 16 + kg * 4 + r, wc + fc * 16 + m, acc[fr][fc][r]);
}

// ---------------------------------------------------------------------------
__global__ void k_diag(float* __restrict__ out, float val)
{
  if (threadIdx.x == 0 && blockIdx.x == 0) out[0] = val;
}

// u[h]=sum_m vs[m]*Wsi[m,h]; w[h]=sum_m vs[m]*Wsh[m,h]; cbd=b_bd.vs (fp64)
__global__ void k_uw(const float* __restrict__ Wsi, const float* __restrict__ Wsh,
                     const float* __restrict__ bbd, const float* __restrict__ vs,
                     double* __restrict__ u, double* __restrict__ wv,
                     double* __restrict__ cbdp)
{
  const int blk = blockIdx.x;
  if (blk < 8) {
    const float* W = (blk < 4) ? Wsi : Wsh;
    double* out = (blk < 4) ? u : wv;
    int h = (blk & 3) * 256 + threadIdx.x;
    double a = 0.0;
    for (int mm = 0; mm < 512; ++mm)
      a += (double)vs[mm] * (double)W[mm * 1024 + h];
    out[h] = a;
  } else if (threadIdx.x < 64) {
    double a = 0.0;
    for (int mm = threadIdx.x; mm < 512; mm += 64)
      a += (double)vs[mm] * (double)bbd[mm];
#pragma unroll
    for (int o = 32; o > 0; o >>= 1) a += __shfl_down(a, o, 64);
    if (threadIdx.x == 0) cbdp[0] = a;
  }
}

// weight split: m 0..1 -> hi+lo, m 2..3 -> hi only (4096x1024 fp32 each)
__global__ void k_wsplit(const float* __restrict__ w1ih, const float* __restrict__ w1hh,
                         const float* __restrict__ w2ih, const float* __restrict__ w2hh,
                         bf16* __restrict__ o1ih_h, bf16* __restrict__ o1ih_l,
                         bf16* __restrict__ o1hh_h, bf16* __restrict__ o1hh_l,
                         bf16* __restrict__ o2ih_h, bf16* __restrict__ o2hh_h)
{
  const int m = blockIdx.x >> 12;
  const size_t i4 = (size_t)(blockIdx.x & 4095) * 256 + threadIdx.x;
  const float* src = (m == 0) ? w1ih : (m == 1) ? w1hh : (m == 2) ? w2ih : w2hh;
  bf16* dh = (m == 0) ? o1ih_h : (m == 1) ? o1hh_h : (m == 2) ? o2ih_h : o2hh_h;
  bf16* dl = (m == 0) ? o1ih_l : (m == 1) ? o1hh_l : nullptr;
  f32x4 v = *(const f32x4*)(src + i4 * 4);
  short4v hv, lv;
#pragma unroll
  for (int j = 0; j < 4; ++j) {
    float x = v[j];
    bf16 h = __float2bfloat16(x);
    hv[j] = __builtin_bit_cast(short, h);
    lv[j] = bfbits(x - __bfloat162float(h));
  }
  *(short4v*)((short*)dh + i4 * 4) = hv;
  if (dl) *(short4v*)((short*)dl + i4 * 4) = lv;
}

// ---------------------------------------------------------------------------
// embed: v = relu(video@Wemb^T+bemb) -> bf16 hi/lo.
// Fused 3-product split GEMM: acc = Ah*Bh + Al*Bh + Ah*Bl in ONE K sweep.
// Per chunk (K=64): load fp32 once, convert hi+lo once, stage 4 LDS tiles
// (Ah|Al|Bh|Bl, 128x64 bf16 each, XOR-swizzled, 64 KB), 3 MFMA products.
// Block = (t, ct): rows = all 128 b for one t, cols ct*128..+128.
// Output row (t & smask)*128 + b.
// ---------------------------------------------------------------------------
__global__ __launch_bounds__(256, 2) void k_embed(
    const float* __restrict__ video, const float* __restrict__ Wemb,
    const float* __restrict__ bemb, bf16* __restrict__ vhi, bf16* __restrict__ vlo,
    int tbase, int smask)
{
  __shared__ __align__(16) short ls[32768];   // Ah 8192 | Al 8192 | Bh 8192 | Bl 8192
  const int t  = tbase + (blockIdx.x >> 3);
  const int ct = blockIdx.x & 7;
  const int tid = threadIdx.x;

  int srow[4], sseg[4], ssw[4];
  const float* arow[4];
  const float* brow[4];
#pragma unroll
  for (int i = 0; i < 4; ++i) {
    int linear = i * 256 + tid;
    srow[i] = linear >> 3;
    sseg[i] = linear & 7;
    ssw[i]  = (sseg[i] ^ (srow[i] & 7)) * 8;
    arow[i] = video + (size_t)(srow[i] * 64 + t) * 2048 + sseg[i] * 8;
    brow[i] = Wemb + (size_t)(ct * 128 + srow[i]) * 2048 + sseg[i] * 8;
  }

  f32x4 acc[4][4] = {};
  const int lane = tid & 63, wave = tid >> 6;
  const int wr = (wave & 1) * 64, wc = (wave >> 1) * 64;
  const int m = lane & 15, kg = lane >> 4;

  short8 ah[4], al[4], bh[4], bl[4];
#pragma unroll
  for (int i = 0; i < 4; ++i) {
    cvt8hl(arow[i], ah[i], al[i]);
    cvt8hl(brow[i], bh[i], bl[i]);
  }
#pragma unroll
  for (int i = 0; i < 4; ++i) {
    *(short8*)(ls +         srow[i] * 64 + ssw[i]) = ah[i];
    *(short8*)(ls +  8192 + srow[i] * 64 + ssw[i]) = al[i];
    *(short8*)(ls + 16384 + srow[i] * 64 + ssw[i]) = bh[i];
    *(short8*)(ls + 24576 + srow[i] * 64 + ssw[i]) = bl[i];
  }
  __syncthreads();

  for (int c = 0; c < 32; ++c) {
    if (c + 1 < 32) {   // register prefetch of next chunk (fp32 -> hi/lo)
#pragma unroll
      for (int i = 0; i < 4; ++i) {
        cvt8hl(arow[i] + (c + 1) * 64, ah[i], al[i]);
        cvt8hl(brow[i] + (c + 1) * 64, bh[i], bl[i]);
      }
    }
#pragma unroll
    for (int ks = 0; ks < 2; ++ks) {
      short8 afh[4], afl[4], bfh[4], bfl[4];
      int asw[4], bsw[4];
#pragma unroll
      for (int f = 0; f < 4; ++f) {
        int ar = wr + f * 16 + m;
        asw[f] = ar * 64 + (((ks * 4 + kg) ^ (ar & 7)) * 8);
        int br = wc + f * 16 + m;
        bsw[f] = br * 64 + (((ks * 4 + kg) ^ (br & 7)) * 8);
        afh[f] = *(const short8*)(ls +         asw[f]);
        bfh[f] = *(const short8*)(ls + 16384 + bsw[f]);
      }
      // hi*hi
#pragma unroll
      for (int fr = 0; fr < 4; ++fr)
#pragma unroll
        for (int fc = 0; fc < 4; ++fc)
          acc[fr][fc] = __builtin_amdgcn_mfma_f32_16x16x32_bf16(afh[fr], bfh[fc], acc[fr][fc], 0, 0, 0);
      // lo*hi
#pragma unroll
      for (int f = 0; f < 4; ++f)
        afl[f] = *(const short8*)(ls + 8192 + asw[f]);
#pragma unroll
      for (int fr = 0; fr < 4; ++fr)
#pragma unroll
        for (int fc = 0; fc < 4; ++fc)
          acc[fr][fc] = __builtin_amdgcn_mfma_f32_16x16x32_bf16(afl[fr], bfh[fc], acc[fr][fc], 0, 0, 0);
      // hi*lo
#pragma unroll
      for (int f = 0; f < 4; ++f)
        bfl[f] = *(const short8*)(ls + 24576 + bsw[f]);
#pragma unroll
      for (int fr = 0; fr < 4; ++fr)
#pragma unroll
        for (int fc = 0; fc < 4; ++fc)
          acc[fr][fc] = __builtin_amdgcn_mfma_f32_16x16x32_bf16(afh[fr], bfl[fc], acc[fr][fc], 0, 0, 0);
    }
    if (c + 1 < 32) {
      __syncthreads();
#pragma unroll
      for (int i = 0; i < 4; ++i) {
        *(short8*)(ls +         srow[i] * 64 + ssw[i]) = ah[i];
        *(short8*)(ls +  8192 + srow[i] * 64 + ssw[i]) = al[i];
        *(short8*)(ls + 16384 + srow[i] * 64 + ssw[i]) = bh[i];
        *(short8*)(ls + 24576 + srow[i] * 64 + ssw[i]) = bl[i];
      }
      __syncthreads();
    }
  }

  const int trow = (t & smask) * 128;
  epilogue(acc, [&](int lrow, int lcol, float aval) {
    int gcol = ct * 128 + lcol;
    float x = fmaxf(aval + bemb[gcol], 0.0f);
    bf16 hi = __float2bfloat16(x);
    size_t o = (size_t)(trow + lrow) * 1024 + gcol;
    vhi[o] = hi;
    vlo[o] = __float2bfloat16(x - __bfloat162float(hi));
  });
}

// zx (fp64): zx[base+rr] = (vhi+vlo)[rr,:] . u + cbd. rows = gridDim*4*16.
__global__ void k_zx(const bf16* __restrict__ vhi, const bf16* __restrict__ vlo,
                     const double* __restrict__ u, const double* __restrict__ cbdp,
                     float* __restrict__ zx, int base)
{
  const int wave = blockIdx.x * 4 + (threadIdx.x >> 6);
  const int lane = threadIdx.x & 63;
  for (int it = 0; it < 16; ++it) {
    int rr = wave * 16 + it;
    double a = 0.0;
#pragma unroll
    for (int q = 0; q < 16; ++q) {
      int h = lane + q * 64;
      size_t o = (size_t)rr * 1024 + h;
      a += (double)(__bfloat162float(vhi[o]) + __bfloat162float(vlo[o])) * u[h];
    }
#pragma unroll
    for (int o = 32; o > 0; o >>= 1) a += __shfl_down(a, o, 64);
    if (lane == 0) zx[base + rr] = (float)(a + cbdp[0]);
  }
}

// ---------------------------------------------------------------------------
// G_k: grid 160, unit u: pr = u>>5 (pair), ct = u&31. Each pair chains two
// K=1024 GEMMs into one accumulator -> P[pr] (row-major 128x4096).
// ---------------------------------------------------------------------------
__global__ __launch_bounds__(256, 2) void k_step(
    const bf16* __restrict__ vhi, const bf16* __restrict__ vlo,
    const bf16* __restrict__ h1r1h, const bf16* __restrict__ h1r1l,
    const bf16* __restrict__ h1r2h, const bf16* __restrict__ h1r2l,
    const bf16* __restrict__ h2h, const bf16* __restrict__ h2l,
    const bf16* __restrict__ w1ih_h, const bf16* __restrict__ w1ih_l,
    const bf16* __restrict__ w1hh_h, const bf16* __restrict__ w1hh_l,
    const bf16* __restrict__ w2ih_h, const bf16* __restrict__ w2hh_h,
    float* __restrict__ R, int k, int smask)
{
  __shared__ __align__(16) short ls[32768];
  const bf16* vh = vhi + (size_t)(k & smask) * 131072;
  const bf16* vl = vlo + (size_t)(k & smask) * 131072;

  const int pr = blockIdx.x >> 5;
  const int ct = blockIdx.x & 31;
  if (k == 0 && pr >= 2) return;    // h-states zero; E_0 reads P0,P1(=p2)
  if (k == 64 && pr < 3) return;    // E_64 only consumes lstm2 partials

  const bf16 *A0, *B0, *A1, *B1;
  switch (pr) {
    case 0:  A0 = vh;    B0 = w1ih_h; A1 = vl;    B1 = w1ih_h; break;
    case 1:  A0 = vh;    B0 = w1ih_l; A1 = h1r1h; B1 = w1hh_h; break;
    case 2:  A0 = h1r1l; B0 = w1hh_h; A1 = h1r1h; B1 = w1hh_l; break;
    case 3:  A0 = h1r2h; B0 = w2ih_h; A1 = h1r2l; B1 = w2ih_h; break;
    default: A0 = h2h;   B0 = w2hh_h; A1 = h2l;   B1 = w2hh_h; break;
  }

  f32x4 acc[4][4] = {};
  gemm_bf16(A0, 1024, B0 + (size_t)ct * 131072, 1024, 16, ls, acc);
  if (!(k == 0 && pr == 1))
    gemm_bf16(A1, 1024, B1 + (size_t)ct * 131072, 1024, 16, ls, acc);

  float* Rout = R + (size_t)pr * 524288;
  epilogue(acc, [&](int lrow, int lcol, float aval) {
    Rout[(size_t)lrow * 4096 + ct * 128 + lcol] = aval;
  });
}

// ---------------------------------------------------------------------------
// E_k: grid 128 (b = blockIdx), 256 threads, 4 j each.
// lstm1 gates = P0 + P1 (+P2 if k>0) + b1; lstm2 gates = P3 + P4.
// ---------------------------------------------------------------------------
__global__ void k_elem(const float* __restrict__ R, const float* __restrict__ zx,
                       float* __restrict__ craw,
                       bf16* __restrict__ h1r1h, bf16* __restrict__ h1r1l,
                       bf16* __restrict__ h1r2h, bf16* __restrict__ h1r2l,
                       float* __restrict__ c2, bf16* __restrict__ h2h, bf16* __restrict__ h2l,
                       float* __restrict__ rdm, const double* __restrict__ wv,
                       const float* __restrict__ b1, float* __restrict__ dout, int k)
{
  __shared__ double red[4];
  const int tid = threadIdx.x;
  const int b   = blockIdx.x;
  const size_t broff = (size_t)b * 4096;
  const float* P0 = R + broff;
  const float* P1 = P0 + 524288;
  const float* P2 = P0 + 2 * 524288;
  const float* P3 = P0 + 3 * 524288;
  const float* P4 = P0 + 4 * 524288;

  if (k < 64) {  // boundary gate + lstm1 step k
    float zpre = zx[k * 128 + b];
    if (k > 0) zpre += rdm[(k - 1) * 128 + b];
    float s  = (sigm(zpre) > 0.5f) ? 1.0f : 0.0f;   // round(): 0.5 -> 0
    float om = 1.0f - s;

    double rd = 0.0;
#pragma unroll
    for (int ji = 0; ji < 4; ++ji) {
      int j = tid + ji * 256;
      float gi = P0[j]        + P1[j]        + b1[j];
      float gf = P0[1024 + j] + P1[1024 + j] + b1[1024 + j];
      float gg = P0[2048 + j] + P1[2048 + j] + b1[2048 + j];
      float go = P0[3072 + j] + P1[3072 + j] + b1[3072 + j];
      if (k > 0) {
        gi += P2[j];
        gf += P2[1024 + j];
        gg += P2[2048 + j];
        go += P2[3072 + j];
      }
      float cn = sigm(gf) * craw[b * 1024 + j] + sigm(gi) * tanhf(gg);
      float hn = sigm(go) * tanhf(cn);
      craw[b * 1024 + j] = om * cn;
      float v1 = om * hn;
      bf16 h1 = __float2bfloat16(v1);
      h1r1h[b * 1024 + j] = h1;
      h1r1l[b * 1024 + j] = __float2bfloat16(v1 - __bfloat162float(h1));
      float v2 = s * hn;
      bf16 h2v = __float2bfloat16(v2);
      h1r2h[b * 1024 + j] = h2v;
      h1r2l[b * 1024 + j] = __float2bfloat16(v2 - __bfloat162float(h2v));
      rd += (double)hn * wv[j];
    }
#pragma unroll
    for (int o = 32; o > 0; o >>= 1) rd += __shfl_down(rd, o, 64);
    if ((tid & 63) == 0) red[tid >> 6] = rd;
    __syncthreads();
    if (tid == 0)
      rdm[k * 128 + b] = om * (float)(red[0] + red[1] + red[2] + red[3]);
  }

  if (k >= 1) {  // lstm2 step k-1 (RBx pre-masked by s_{k-1}; bias-free)
#pragma unroll
    for (int ji = 0; ji < 4; ++ji) {
      int j = tid + ji * 256;
      float gi = P3[j]        + P4[j];
      float gf = P3[1024 + j] + P4[1024 + j];
      float gg = P3[2048 + j] + P4[2048 + j];
      float go = P3[3072 + j] + P4[3072 + j];
      float cn = sigm(gf) * c2[b * 1024 + j] + sigm(gi) * tanhf(gg);
      float hn = sigm(go) * tanhf(cn);
      c2[b * 1024 + j] = cn;
      bf16 hh = __float2bfloat16(hn);
      h2h[b * 1024 + j] = hh;
      h2l[b * 1024 + j] = __float2bfloat16(hn - __bfloat162float(hh));
      if (k == 64) dout[b * 1024 + j] = hn;
    }
  }
}

// ---------------------------------------------------------------------------
extern "C" void kernel_launch(void* const* d_in, const int* in_sizes, int n_in,
                              void* d_out, int out_size, void* d_ws, size_t ws_size,
                              hipStream_t stream) {
  const float* video = (const float*)d_in[0];
  const float* Wemb  = (const float*)d_in[1];
  const float* bemb  = (const float*)d_in[2];
  const float* Wih1  = (const float*)d_in[3];
  const float* Whh1  = (const float*)d_in[4];
  const float* b1    = (const float*)d_in[5];
  const float* Wsi   = (const float*)d_in[6];
  const float* Wsh   = (const float*)d_in[7];
  const float* bbd   = (const float*)d_in[8];
  const float* vs    = (const float*)d_in[9];
  const float* Wih2  = (const float*)d_in[10];
  const float* Whh2  = (const float*)d_in[11];
  float* dout = (float*)d_out;

  static const int exp_sizes[12] = {
    128 * 64 * 2048, 1024 * 2048, 1024, 4096 * 1024, 4096 * 1024, 4096,
    512 * 1024, 512 * 1024, 512, 512, 4096 * 1024, 4096 * 1024 };
  int bad = -1;
  if (n_in != 12) bad = 99;
  else if (out_size != 131072) bad = 98;
  else
    for (int i = 0; i < 12; ++i)
      if (in_sizes[i] != exp_sizes[i]) { bad = i; break; }
  if (bad >= 0) {
    k_diag<<<1, 64, 0, stream>>>(dout, 10000.0f + (float)bad);
    return;
  }

  char* ws = (char*)d_ws;
  size_t off = 0;
  auto alloc = [&](size_t bytes) {
    char* p = ws + off;
    off += (bytes + 255) & ~(size_t)255;
    return p;
  };
  // zero region (state), memset each launch
  bf16*  h1r1h = (bf16*)alloc(262144);
  bf16*  h1r1l = (bf16*)alloc(262144);
  bf16*  h1r2h = (bf16*)alloc(262144);
  bf16*  h1r2l = (bf16*)alloc(262144);
  bf16*  h2h   = (bf16*)alloc(262144);
  bf16*  h2l   = (bf16*)alloc(262144);
  float* c2    = (float*)alloc(524288);
  float* craw  = (float*)alloc(524288);
  const size_t zeroBytes = off;
  // rest (written before read every launch)
  double* u    = (double*)alloc(8192);
  double* wvv  = (double*)alloc(8192);
  double* cbdp = (double*)alloc(256);
  float* rdm   = (float*)alloc(64 * 128 * 4);
  float* zx    = (float*)alloc(8192 * 4);
  bf16* w1ih_h = (bf16*)alloc(8388608);
  bf16* w1ih_l = (bf16*)alloc(8388608);
  bf16* w1hh_h = (bf16*)alloc(8388608);
  bf16* w1hh_l = (bf16*)alloc(8388608);
  bf16* w2ih_h = (bf16*)alloc(8388608);
  bf16* w2hh_h = (bf16*)alloc(8388608);
  float* R     = (float*)alloc(5 * 524288 * 4);   // 5 paired partials, 10.5 MB
  const size_t fixedBytes = off;

  // v ring: pick the largest power-of-two slot count that fits (64 = full-v).
  const size_t perSlot = (size_t)131072 * 2 * 2;   // vhi+vlo bytes per slot
  int slots = 64;
  while (slots > 8 && fixedBytes + (size_t)slots * perSlot + 512 > ws_size)
    slots >>= 1;
  if (fixedBytes + (size_t)8 * perSlot + 512 > ws_size) {
    k_diag<<<1, 64, 0, stream>>>(dout, 100.0f + (float)(ws_size >> 20));
    return;
  }
  const int smask = slots - 1;
  bf16* vhi = (bf16*)alloc((size_t)slots * 131072 * 2);
  bf16* vlo = (bf16*)alloc((size_t)slots * 131072 * 2);

  (void)hipMemsetAsync(d_ws, 0, zeroBytes, stream);
  k_uw<<<9, 256, 0, stream>>>(Wsi, Wsh, bbd, vs, u, wvv, cbdp);
  k_wsplit<<<16384, 256, 0, stream>>>(Wih1, Whh1, Wih2, Whh2,
                                      w1ih_h, w1ih_l, w1hh_h, w1hh_l, w2ih_h, w2hh_h);
  if (slots == 64) {
    k_embed<<<512, 256, 0, stream>>>(video, Wemb, bemb, vhi, vlo, 0, smask);
    k_zx<<<128, 256, 0, stream>>>(vhi, vlo, u, cbdp, zx, 0);
  }

  for (int k = 0; k <= 64; ++k) {
    if (slots < 64 && k < 64 && (k & smask) == 0) {
      k_embed<<<slots * 8, 256, 0, stream>>>(video, Wemb, bemb, vhi, vlo, k, smask);
      k_zx<<<slots * 2, 256, 0, stream>>>(vhi, vlo, u, cbdp, zx, k * 128);
    }
    k_step<<<160, 256, 0, stream>>>(vhi, vlo, h1r1h, h1r1l, h1r2h, h1r2l, h2h, h2l,
                                    w1ih_h, w1ih_l, w1hh_h, w1hh_l, w2ih_h, w2hh_h,
                                    R, k, smask);
    k_elem<<<128, 256, 0, stream>>>(R, zx, craw, h1r1h, h1r1l, h1r2h, h1r2l,
                                    c2, h2h, h2l, rdm, wvv, b1, dout, k);
  }
}